// Round 5
// baseline (373.697 us; speedup 1.0000x reference)
//
#include <hip/hip_runtime.h>
#include <hip/hip_bf16.h>
#include <math.h>

// Problem constants
#define D_MODEL 768
#define D_STATE 16
#define D_CONV  4
#define D_INNER 1536
#define BATCH   2
#define SEQ     2048
#define MROWS   (BATCH * SEQ)        // 4096
#define NXZ     (2 * D_INNER)        // 3072
#define NSSM    (2 * D_STATE + 1)    // 33
#define BD      (BATCH * D_INNER)    // 3072

// Chunked scan parameters
#define NCH 64
#define LCH (SEQ / NCH)              // 32
#define NS  (BATCH * D_INNER * D_STATE)  // 49152

typedef short s8v __attribute__((ext_vector_type(8)));   // 8 bf16 (4 VGPRs)
typedef float f4v __attribute__((ext_vector_type(4)));   // 4 fp32 acc

// ---------------------------------------------------------------------------
// bf16 split helpers
// ---------------------------------------------------------------------------
__device__ __forceinline__ unsigned short f2bf_rne(float f) {
    unsigned int x = __float_as_uint(f);
    unsigned int r = (x + 0x7FFFu + ((x >> 16) & 1u)) >> 16;
    return (unsigned short)r;
}
__device__ __forceinline__ float bf2f(unsigned short h) {
    return __uint_as_float(((unsigned int)h) << 16);
}

__device__ __forceinline__ void gl_lds16(const unsigned short* g, unsigned short* l) {
    __builtin_amdgcn_global_load_lds(
        (const __attribute__((address_space(1))) void*)g,
        (__attribute__((address_space(3))) void*)l, 16, 0, 0);
}

// ---------------------------------------------------------------------------
// split_retile: src fp32 [R x K] row-major -> dh/dl bf16 in GEMM-tiled layout
// off(m,k) = ((kb*(R/16)+mb)*16+mr)*32 + (kc ^ ((mr>>1)&3))*8 + kj
// ---------------------------------------------------------------------------
__global__ __launch_bounds__(256) void split_retile(
    const float* __restrict__ src, unsigned short* __restrict__ dh,
    unsigned short* __restrict__ dl, int R, int K)
{
    const int o = blockIdx.x * 256 + threadIdx.x;
    const int kj = o & 7;
    const int cp = (o >> 3) & 3;
    const int mr = (o >> 5) & 15;
    const int rest = o >> 9;
    const int Rb = R >> 4;
    const int mb = rest % Rb;
    const int kb = rest / Rb;
    const int kc = cp ^ ((mr >> 1) & 3);
    const int m = (mb << 4) + mr;
    const int k = (kb << 5) + (kc << 3) + kj;
    const float v = src[(size_t)m * K + k];
    const unsigned short h = f2bf_rne(v);
    dh[o] = h;
    dl[o] = f2bf_rne(v - bf2f(h));
}

// ---------------------------------------------------------------------------
// Split-bf16 MFMA GEMM: C[M,N] = A[M,K] @ W[N,K]^T + bias (pre-retiled A,W)
// ---------------------------------------------------------------------------
template<int BMt, int BNt, int MINBPCU>
__global__ __launch_bounds__(256, MINBPCU) void gemm_split(
    const unsigned short* __restrict__ Ah, const unsigned short* __restrict__ Al,
    const unsigned short* __restrict__ Bh, const unsigned short* __restrict__ Bl,
    const float* __restrict__ bias, float* __restrict__ C,
    int M, int N, int K)
{
    constexpr int MT = BMt / 32;
    constexpr int NT = BNt / 32;

    __shared__ unsigned short lsAh[BMt * 32];
    __shared__ unsigned short lsAl[BMt * 32];
    __shared__ unsigned short lsBh[BNt * 32];
    __shared__ unsigned short lsBl[BNt * 32];

    const int tid = threadIdx.x;
    const int w = tid >> 6, lane = tid & 63;
    const int wr = w >> 1, wc = w & 1;
    const int row16 = lane & 15, quad = lane >> 4;
    const int bm = blockIdx.y, bn = blockIdx.x;
    const int Mb = M >> 4, Nb = N >> 4;
    const int mb0 = bm * (BMt / 16), nb0 = bn * (BNt / 16);

    f4v acc[MT][NT];
    const f4v zero4 = {0.f, 0.f, 0.f, 0.f};
#pragma unroll
    for (int i = 0; i < MT; ++i)
#pragma unroll
        for (int j = 0; j < NT; ++j) acc[i][j] = zero4;

    const int swz = (row16 >> 1) & 3;
    int aoff[MT], boff[NT];
#pragma unroll
    for (int i = 0; i < MT; ++i)
        aoff[i] = (((wr * MT + i) * 16 + row16) << 5) + ((quad ^ swz) << 3);
#pragma unroll
    for (int j = 0; j < NT; ++j)
        boff[j] = (((wc * NT + j) * 16 + row16) << 5) + ((quad ^ swz) << 3);

    const int nkb = K >> 5;
    for (int kb = 0; kb < nkb; ++kb) {
        __syncthreads();
        {
            const size_t ka = (size_t)kb * Mb + mb0;
#pragma unroll
            for (int c = w; c < BMt / 16; c += 4) {
                gl_lds16(Ah + ((ka + c) << 9) + lane * 8, &lsAh[c << 9]);
                gl_lds16(Al + ((ka + c) << 9) + lane * 8, &lsAl[c << 9]);
            }
            const size_t kB = (size_t)kb * Nb + nb0;
#pragma unroll
            for (int c = w; c < BNt / 16; c += 4) {
                gl_lds16(Bh + ((kB + c) << 9) + lane * 8, &lsBh[c << 9]);
                gl_lds16(Bl + ((kB + c) << 9) + lane * 8, &lsBl[c << 9]);
            }
        }
        __syncthreads();

        s8v ah[MT], al[MT], bh[NT], bl[NT];
#pragma unroll
        for (int i = 0; i < MT; ++i) {
            ah[i] = *(const s8v*)&lsAh[aoff[i]];
            al[i] = *(const s8v*)&lsAl[aoff[i]];
        }
#pragma unroll
        for (int j = 0; j < NT; ++j) {
            bh[j] = *(const s8v*)&lsBh[boff[j]];
            bl[j] = *(const s8v*)&lsBl[boff[j]];
        }
#pragma unroll
        for (int i = 0; i < MT; ++i)
#pragma unroll
            for (int j = 0; j < NT; ++j) {
                acc[i][j] = __builtin_amdgcn_mfma_f32_16x16x32_bf16(
                    al[i], bh[j], acc[i][j], 0, 0, 0);
                acc[i][j] = __builtin_amdgcn_mfma_f32_16x16x32_bf16(
                    ah[i], bl[j], acc[i][j], 0, 0, 0);
                acc[i][j] = __builtin_amdgcn_mfma_f32_16x16x32_bf16(
                    ah[i], bh[j], acc[i][j], 0, 0, 0);
            }
    }

#pragma unroll
    for (int j = 0; j < NT; ++j) {
        const int col = bn * BNt + (wc * NT + j) * 16 + row16;
        const float bc = bias[col];
#pragma unroll
        for (int i = 0; i < MT; ++i) {
            const int row0 = bm * BMt + (wr * MT + i) * 16 + quad * 4;
#pragma unroll
            for (int r = 0; r < 4; ++r)
                C[(size_t)(row0 + r) * N + col] = acc[i][j][r] + bc;
        }
    }
}

// ---------------------------------------------------------------------------
// Depthwise causal conv (k=4) + bias + SiLU.  xconv[bt, d]
// ---------------------------------------------------------------------------
__global__ __launch_bounds__(256) void conv_silu_kernel(
    const float* __restrict__ xz, const float* __restrict__ cw,
    const float* __restrict__ cb, float* __restrict__ out)
{
    const int idx = blockIdx.x * 256 + threadIdx.x;
    const int d = idx % D_INNER;
    const int bt = idx / D_INNER;
    const int t = bt & (SEQ - 1);

    const float w0 = cw[d * 4 + 0];
    const float w1 = cw[d * 4 + 1];
    const float w2 = cw[d * 4 + 2];
    const float w3 = cw[d * 4 + 3];

    float acc = cb[d];
    const size_t base = (size_t)bt * NXZ + d;
    if (t >= 3) acc = fmaf(xz[base - 3 * (size_t)NXZ], w0, acc);
    if (t >= 2) acc = fmaf(xz[base - 2 * (size_t)NXZ], w1, acc);
    if (t >= 1) acc = fmaf(xz[base - 1 * (size_t)NXZ], w2, acc);
    acc = fmaf(xz[base], w3, acc);

    out[idx] = acc / (1.f + __expf(-acc));
}

// ---------------------------------------------------------------------------
// x-proj v2: 16 rows per block, 4 rows per wave; one W-fragment load feeds
// 4 row-FMAs (4x less L2 traffic on xp_W than wave-per-row).
// ---------------------------------------------------------------------------
__global__ __launch_bounds__(256) void xproj_kernel(
    const float* __restrict__ X, const float* __restrict__ W,
    const float* __restrict__ b, float* __restrict__ out)
{
    const int w = threadIdx.x >> 6;
    const int lane = threadIdx.x & 63;
    const int row0 = blockIdx.x * 16 + w * 4;

    float xr[4][24];
#pragma unroll
    for (int r = 0; r < 4; ++r)
#pragma unroll
        for (int i = 0; i < 24; ++i)
            xr[r][i] = X[(size_t)(row0 + r) * D_INNER + lane + i * 64];

    for (int n = 0; n < NSSM; ++n) {
        const float* wrow = W + (size_t)n * D_INNER;
        float a0 = 0.f, a1 = 0.f, a2 = 0.f, a3 = 0.f;
#pragma unroll
        for (int i = 0; i < 24; ++i) {
            const float wv = wrow[lane + i * 64];
            a0 = fmaf(xr[0][i], wv, a0);
            a1 = fmaf(xr[1][i], wv, a1);
            a2 = fmaf(xr[2][i], wv, a2);
            a3 = fmaf(xr[3][i], wv, a3);
        }
        const float bn_ = b[n];
        float accv[4] = {a0, a1, a2, a3};
#pragma unroll
        for (int r = 0; r < 4; ++r) {
            float a = accv[r];
            a += __shfl_xor(a, 32);
            a += __shfl_xor(a, 16);
            a += __shfl_xor(a, 8);
            a += __shfl_xor(a, 4);
            a += __shfl_xor(a, 2);
            a += __shfl_xor(a, 1);
            if (lane == 0) out[(size_t)(row0 + r) * NSSM + n] = a + bn_;
        }
    }
}

// ---------------------------------------------------------------------------
// Chunked selective scan, thread-per-channel layout (16 states in registers).
// addr(c,n,b,d) = c*NS + n*BD + b*D_INNER + d  (coalesced in d per n).
// ---------------------------------------------------------------------------
__global__ __launch_bounds__(256) void scan_phase1(
    const float* __restrict__ xssm, const float* __restrict__ xconv,
    const float* __restrict__ dpW, const float* __restrict__ dpb,
    const float* __restrict__ A_log,
    float* __restrict__ Ap, float* __restrict__ Hp)
{
    const int d = blockIdx.x * 256 + threadIdx.x;
    const int c = blockIdx.y;
    const int b = blockIdx.z;

    const float w  = dpW[d];
    const float bb = dpb[d];
    float An[D_STATE];
#pragma unroll
    for (int n = 0; n < D_STATE; ++n)
        An[n] = -__expf(A_log[d * D_STATE + n]);

    const int bt0 = b * SEQ + c * LCH;

    float h[D_STATE], ap[D_STATE];
#pragma unroll
    for (int n = 0; n < D_STATE; ++n) { h[n] = 0.f; ap[n] = 1.f; }

    float xv = xconv[(size_t)bt0 * D_INNER + d];
    for (int t = 0; t < LCH; ++t) {
        const int tn = (t + 1 < LCH) ? (t + 1) : t;
        const float xv_nxt = xconv[(size_t)(bt0 + tn) * D_INNER + d];

        const float* row = xssm + (size_t)(bt0 + t) * NSSM;  // wave-uniform
        const float dr = row[32];
        const float u = fmaf(dr, w, bb);
        const float delta = __logf(1.f + __expf(u));
        const float dx = delta * xv;
#pragma unroll
        for (int n = 0; n < D_STATE; ++n) {
            const float dA = __expf(delta * An[n]);
            h[n] = fmaf(dA, h[n], dx * row[n]);
            ap[n] *= dA;
        }
        xv = xv_nxt;
    }

    const size_t bd = (size_t)b * D_INNER + d;
#pragma unroll
    for (int n = 0; n < D_STATE; ++n) {
        Ap[(size_t)c * NS + (size_t)n * BD + bd] = ap[n];
        Hp[(size_t)c * NS + (size_t)n * BD + bd] = h[n];
    }
}

__global__ __launch_bounds__(256) void scan_phase2(
    float* __restrict__ Ap, const float* __restrict__ Hp)
{
    const size_t s = (size_t)blockIdx.x * 256 + threadIdx.x;
    float carry = 0.f;
#pragma unroll 4
    for (int c = 0; c < NCH; ++c) {
        const float a  = Ap[(size_t)c * NS + s];
        const float hp = Hp[(size_t)c * NS + s];
        Ap[(size_t)c * NS + s] = carry;
        carry = fmaf(a, carry, hp);
    }
}

__global__ __launch_bounds__(256) void scan_phase3(
    const float* __restrict__ xssm, float* __restrict__ xconv,
    const float* __restrict__ xz,
    const float* __restrict__ dpW, const float* __restrict__ dpb,
    const float* __restrict__ A_log, const float* __restrict__ Dvec,
    const float* __restrict__ Hs)
{
    const int d = blockIdx.x * 256 + threadIdx.x;
    const int c = blockIdx.y;
    const int b = blockIdx.z;

    const float w  = dpW[d];
    const float bb = dpb[d];
    const float Dd = Dvec[d];
    float An[D_STATE];
#pragma unroll
    for (int n = 0; n < D_STATE; ++n)
        An[n] = -__expf(A_log[d * D_STATE + n]);

    const int bt0 = b * SEQ + c * LCH;
    const size_t bd = (size_t)b * D_INNER + d;

    float h[D_STATE];
#pragma unroll
    for (int n = 0; n < D_STATE; ++n)
        h[n] = Hs[(size_t)c * NS + (size_t)n * BD + bd];

    float xv = xconv[(size_t)bt0 * D_INNER + d];
    float zv = xz[(size_t)bt0 * NXZ + D_INNER + d];
    for (int t = 0; t < LCH; ++t) {
        const int tn = (t + 1 < LCH) ? (t + 1) : t;
        const float xv_nxt = xconv[(size_t)(bt0 + tn) * D_INNER + d];
        const float zv_nxt = xz[(size_t)(bt0 + tn) * NXZ + D_INNER + d];

        const float* row = xssm + (size_t)(bt0 + t) * NSSM;  // wave-uniform
        const float dr = row[32];
        const float u = fmaf(dr, w, bb);
        const float delta = __logf(1.f + __expf(u));
        const float dx = delta * xv;

        float y = 0.f;
#pragma unroll
        for (int n = 0; n < D_STATE; ++n) {
            const float dA = __expf(delta * An[n]);
            h[n] = fmaf(dA, h[n], dx * row[n]);
            y = fmaf(row[16 + n], h[n], y);
        }
        y = fmaf(xv, Dd, y);
        const float sg = zv / (1.f + __expf(-zv));
        xconv[(size_t)(bt0 + t) * D_INNER + d] = y * sg;

        xv = xv_nxt; zv = zv_nxt;
    }
}

// ---------------------------------------------------------------------------
extern "C" void kernel_launch(void* const* d_in, const int* in_sizes, int n_in,
                              void* d_out, int out_size, void* d_ws, size_t ws_size,
                              hipStream_t stream)
{
    const float* x      = (const float*)d_in[0];
    const float* in_W   = (const float*)d_in[1];
    const float* in_b   = (const float*)d_in[2];
    const float* conv_W = (const float*)d_in[3];
    const float* conv_b = (const float*)d_in[4];
    const float* xp_W   = (const float*)d_in[5];
    const float* xp_b   = (const float*)d_in[6];
    const float* dp_W   = (const float*)d_in[7];
    const float* dp_b   = (const float*)d_in[8];
    const float* A_log  = (const float*)d_in[9];
    const float* Dvec   = (const float*)d_in[10];
    const float* out_W  = (const float*)d_in[11];
    const float* out_b  = (const float*)d_in[12];
    float* out = (float*)d_out;

    // workspace layout (float units)
    float* ws    = (float*)d_ws;
    float* xz    = ws;                                       // 12,582,912
    float* xconv = xz + (size_t)MROWS * NXZ;                 //  6,291,456
    float* xssm  = xconv + (size_t)MROWS * D_INNER;          //    135,168
    float* Hp    = xssm + (size_t)MROWS * NSSM;              //  3,145,728
    unsigned short* inWh  = (unsigned short*)(Hp + (size_t)NCH * NS);
    unsigned short* inWl  = inWh + (size_t)NXZ * D_MODEL;
    unsigned short* outWh = inWl + (size_t)NXZ * D_MODEL;
    unsigned short* outWl = outWh + (size_t)D_MODEL * D_INNER;
    float* ws_end = (float*)(outWl + (size_t)D_MODEL * D_INNER);

    // Ap (NCH*NS floats = 12.58 MB): prefer workspace if it fits, else d_out
    // (dead scratch between gemm1 consuming xh/xl and the final GEMM write).
    const size_t used_floats = (size_t)(ws_end - ws);
    const bool ap_in_ws = ws_size >= (used_floats + (size_t)NCH * NS) * sizeof(float);
    float* Ap = ap_in_ws ? ws_end : (float*)d_out;

    // x-split lives in d_out (consumed by gemm1 before Ap could be written)
    unsigned short* xh = (unsigned short*)d_out;
    unsigned short* xl = xh + (size_t)MROWS * D_MODEL;
    // xcg-split aliases the (dead-after-phase3) xz region
    unsigned short* xcgh = (unsigned short*)xz;
    unsigned short* xcgl = xcgh + (size_t)MROWS * D_INNER;

    // 0) split+retile x, in_W, out_W
    split_retile<<<(MROWS * D_MODEL) / 256, 256, 0, stream>>>(x, xh, xl, MROWS, D_MODEL);
    split_retile<<<(NXZ * D_MODEL) / 256, 256, 0, stream>>>(in_W, inWh, inWl, NXZ, D_MODEL);
    split_retile<<<(D_MODEL * D_INNER) / 256, 256, 0, stream>>>(out_W, outWh, outWl, D_MODEL, D_INNER);

    // 1) in-proj: xz = x @ in_W^T + in_b   (M=4096, N=3072, K=768)
    // 128x64 tile -> 1536 blocks (6/CU target, 5 guaranteed via launch_bounds)
    {
        dim3 grid(NXZ / 64, MROWS / 128);
        gemm_split<128, 64, 5><<<grid, 256, 0, stream>>>(
            xh, xl, inWh, inWl, in_b, xz, MROWS, NXZ, D_MODEL);
    }
    // 2) depthwise conv + SiLU
    conv_silu_kernel<<<(MROWS * D_INNER) / 256, 256, 0, stream>>>(xz, conv_W, conv_b, xconv);
    // 3) x-proj
    xproj_kernel<<<MROWS / 16, 256, 0, stream>>>(xconv, xp_W, xp_b, xssm);
    // 4) chunked selective scan (thread-per-channel, registers for 16 states)
    {
        dim3 grid13(D_INNER / 256, NCH, BATCH);
        scan_phase1<<<grid13, 256, 0, stream>>>(xssm, xconv, dp_W, dp_b, A_log, Ap, Hp);
        scan_phase2<<<NS / 256, 256, 0, stream>>>(Ap, Hp);
        scan_phase3<<<grid13, 256, 0, stream>>>(xssm, xconv, xz, dp_W, dp_b, A_log,
                                                Dvec, Ap);
    }
    // 5) split+retile gated output (xz region is dead now)
    split_retile<<<(MROWS * D_INNER) / 256, 256, 0, stream>>>(xconv, xcgh, xcgl, MROWS, D_INNER);
    // 6) out-proj: out = y @ out_W^T + out_b  (M=4096, N=768, K=1536)
    {
        dim3 grid(D_MODEL / 64, MROWS / 64);
        gemm_split<64, 64, 1><<<grid, 256, 0, stream>>>(
            xcgh, xcgl, outWh, outWl, out_b, out, MROWS, D_MODEL, D_INNER);
    }
}

// Round 6
// 354.282 us; speedup vs baseline: 1.0548x; 1.0548x over previous
//
#include <hip/hip_runtime.h>
#include <hip/hip_bf16.h>
#include <math.h>

// Problem constants
#define D_MODEL 768
#define D_STATE 16
#define D_CONV  4
#define D_INNER 1536
#define BATCH   2
#define SEQ     2048
#define MROWS   (BATCH * SEQ)        // 4096
#define NXZ     (2 * D_INNER)        // 3072
#define NSSM    (2 * D_STATE + 1)    // 33
#define BD      (BATCH * D_INNER)    // 3072

// Chunked scan parameters
#define NCH 64
#define LCH (SEQ / NCH)              // 32
#define NS  (BATCH * D_INNER * D_STATE)  // 49152

typedef short s8v __attribute__((ext_vector_type(8)));   // 8 bf16 (4 VGPRs)
typedef float f4v __attribute__((ext_vector_type(4)));   // 4 fp32 acc

// ---------------------------------------------------------------------------
// bf16 split helpers
// ---------------------------------------------------------------------------
__device__ __forceinline__ unsigned short f2bf_rne(float f) {
    unsigned int x = __float_as_uint(f);
    unsigned int r = (x + 0x7FFFu + ((x >> 16) & 1u)) >> 16;
    return (unsigned short)r;
}
__device__ __forceinline__ float bf2f(unsigned short h) {
    return __uint_as_float(((unsigned int)h) << 16);
}

__device__ __forceinline__ void gl_lds16(const unsigned short* g, unsigned short* l) {
    __builtin_amdgcn_global_load_lds(
        (const __attribute__((address_space(1))) void*)g,
        (__attribute__((address_space(3))) void*)l, 16, 0, 0);
}

// ---------------------------------------------------------------------------
// split_retile: src fp32 [R x K] row-major -> dh/dl bf16 in GEMM-tiled layout
// off(m,k) = ((kb*(R/16)+mb)*16+mr)*32 + (kc ^ ((mr>>1)&3))*8 + kj
// ---------------------------------------------------------------------------
__global__ __launch_bounds__(256) void split_retile(
    const float* __restrict__ src, unsigned short* __restrict__ dh,
    unsigned short* __restrict__ dl, int R, int K)
{
    const int o = blockIdx.x * 256 + threadIdx.x;
    const int kj = o & 7;
    const int cp = (o >> 3) & 3;
    const int mr = (o >> 5) & 15;
    const int rest = o >> 9;
    const int Rb = R >> 4;
    const int mb = rest % Rb;
    const int kb = rest / Rb;
    const int kc = cp ^ ((mr >> 1) & 3);
    const int m = (mb << 4) + mr;
    const int k = (kb << 5) + (kc << 3) + kj;
    const float v = src[(size_t)m * K + k];
    const unsigned short h = f2bf_rne(v);
    dh[o] = h;
    dl[o] = f2bf_rne(v - bf2f(h));
}

// ---------------------------------------------------------------------------
// Split-bf16 MFMA GEMM: C[M,N] = A[M,K] @ W[N,K]^T + bias (pre-retiled A,W)
// 128x128 is the balanced config: 48 MFMA (~230cyc) vs 16 ds_read_b128
// (~192cyc) per wave-kstep.  (128x64 proved ds_read-bound: R5 regression.)
// ---------------------------------------------------------------------------
template<int BMt, int BNt>
__global__ __launch_bounds__(256) void gemm_split(
    const unsigned short* __restrict__ Ah, const unsigned short* __restrict__ Al,
    const unsigned short* __restrict__ Bh, const unsigned short* __restrict__ Bl,
    const float* __restrict__ bias, float* __restrict__ C,
    int M, int N, int K)
{
    constexpr int MT = BMt / 32;
    constexpr int NT = BNt / 32;

    __shared__ unsigned short lsAh[BMt * 32];
    __shared__ unsigned short lsAl[BMt * 32];
    __shared__ unsigned short lsBh[BNt * 32];
    __shared__ unsigned short lsBl[BNt * 32];

    const int tid = threadIdx.x;
    const int w = tid >> 6, lane = tid & 63;
    const int wr = w >> 1, wc = w & 1;
    const int row16 = lane & 15, quad = lane >> 4;
    const int bm = blockIdx.y, bn = blockIdx.x;
    const int Mb = M >> 4, Nb = N >> 4;
    const int mb0 = bm * (BMt / 16), nb0 = bn * (BNt / 16);

    f4v acc[MT][NT];
    const f4v zero4 = {0.f, 0.f, 0.f, 0.f};
#pragma unroll
    for (int i = 0; i < MT; ++i)
#pragma unroll
        for (int j = 0; j < NT; ++j) acc[i][j] = zero4;

    const int swz = (row16 >> 1) & 3;
    int aoff[MT], boff[NT];
#pragma unroll
    for (int i = 0; i < MT; ++i)
        aoff[i] = (((wr * MT + i) * 16 + row16) << 5) + ((quad ^ swz) << 3);
#pragma unroll
    for (int j = 0; j < NT; ++j)
        boff[j] = (((wc * NT + j) * 16 + row16) << 5) + ((quad ^ swz) << 3);

    const int nkb = K >> 5;
    for (int kb = 0; kb < nkb; ++kb) {
        __syncthreads();
        {
            const size_t ka = (size_t)kb * Mb + mb0;
#pragma unroll
            for (int c = w; c < BMt / 16; c += 4) {
                gl_lds16(Ah + ((ka + c) << 9) + lane * 8, &lsAh[c << 9]);
                gl_lds16(Al + ((ka + c) << 9) + lane * 8, &lsAl[c << 9]);
            }
            const size_t kB = (size_t)kb * Nb + nb0;
#pragma unroll
            for (int c = w; c < BNt / 16; c += 4) {
                gl_lds16(Bh + ((kB + c) << 9) + lane * 8, &lsBh[c << 9]);
                gl_lds16(Bl + ((kB + c) << 9) + lane * 8, &lsBl[c << 9]);
            }
        }
        __syncthreads();

        s8v ah[MT], al[MT], bh[NT], bl[NT];
#pragma unroll
        for (int i = 0; i < MT; ++i) {
            ah[i] = *(const s8v*)&lsAh[aoff[i]];
            al[i] = *(const s8v*)&lsAl[aoff[i]];
        }
#pragma unroll
        for (int j = 0; j < NT; ++j) {
            bh[j] = *(const s8v*)&lsBh[boff[j]];
            bl[j] = *(const s8v*)&lsBl[boff[j]];
        }
#pragma unroll
        for (int i = 0; i < MT; ++i)
#pragma unroll
            for (int j = 0; j < NT; ++j) {
                acc[i][j] = __builtin_amdgcn_mfma_f32_16x16x32_bf16(
                    al[i], bh[j], acc[i][j], 0, 0, 0);
                acc[i][j] = __builtin_amdgcn_mfma_f32_16x16x32_bf16(
                    ah[i], bl[j], acc[i][j], 0, 0, 0);
                acc[i][j] = __builtin_amdgcn_mfma_f32_16x16x32_bf16(
                    ah[i], bh[j], acc[i][j], 0, 0, 0);
            }
    }

#pragma unroll
    for (int j = 0; j < NT; ++j) {
        const int col = bn * BNt + (wc * NT + j) * 16 + row16;
        const float bc = bias[col];
#pragma unroll
        for (int i = 0; i < MT; ++i) {
            const int row0 = bm * BMt + (wr * MT + i) * 16 + quad * 4;
#pragma unroll
            for (int r = 0; r < 4; ++r)
                C[(size_t)(row0 + r) * N + col] = acc[i][j][r] + bc;
        }
    }
}

// ---------------------------------------------------------------------------
// Depthwise causal conv (k=4) + bias + SiLU, float4 over d (4 channels/thread)
// ---------------------------------------------------------------------------
__global__ __launch_bounds__(256) void conv_silu_kernel(
    const float* __restrict__ xz, const float* __restrict__ cw,
    const float* __restrict__ cb, float* __restrict__ out)
{
    const int q = blockIdx.x * 256 + threadIdx.x;      // 0 .. MROWS*D_INNER/4
    const int dq = q % (D_INNER / 4);
    const int bt = q / (D_INNER / 4);
    const int t = bt & (SEQ - 1);
    const int d = dq * 4;

    const float4 w0 = *(const float4*)&cw[(d + 0) * 4];
    const float4 w1 = *(const float4*)&cw[(d + 1) * 4];
    const float4 w2 = *(const float4*)&cw[(d + 2) * 4];
    const float4 w3 = *(const float4*)&cw[(d + 3) * 4];
    const float4 bc = *(const float4*)&cb[d];

    const size_t base = (size_t)bt * NXZ + d;
    float4 a = bc;
    if (t >= 3) {
        const float4 v = *(const float4*)&xz[base - 3 * (size_t)NXZ];
        a.x = fmaf(v.x, w0.x, a.x); a.y = fmaf(v.y, w1.x, a.y);
        a.z = fmaf(v.z, w2.x, a.z); a.w = fmaf(v.w, w3.x, a.w);
    }
    if (t >= 2) {
        const float4 v = *(const float4*)&xz[base - 2 * (size_t)NXZ];
        a.x = fmaf(v.x, w0.y, a.x); a.y = fmaf(v.y, w1.y, a.y);
        a.z = fmaf(v.z, w2.y, a.z); a.w = fmaf(v.w, w3.y, a.w);
    }
    if (t >= 1) {
        const float4 v = *(const float4*)&xz[base - 1 * (size_t)NXZ];
        a.x = fmaf(v.x, w0.z, a.x); a.y = fmaf(v.y, w1.z, a.y);
        a.z = fmaf(v.z, w2.z, a.z); a.w = fmaf(v.w, w3.z, a.w);
    }
    {
        const float4 v = *(const float4*)&xz[base];
        a.x = fmaf(v.x, w0.w, a.x); a.y = fmaf(v.y, w1.w, a.y);
        a.z = fmaf(v.z, w2.w, a.z); a.w = fmaf(v.w, w3.w, a.w);
    }
    float4 o;
    o.x = a.x / (1.f + __expf(-a.x));
    o.y = a.y / (1.f + __expf(-a.y));
    o.z = a.z / (1.f + __expf(-a.z));
    o.w = a.w / (1.f + __expf(-a.w));
    *(float4*)&out[(size_t)bt * D_INNER + d] = o;
}

// ---------------------------------------------------------------------------
// x-proj: 16 rows per block, 4 rows per wave; one W fragment feeds 4 row-FMAs
// ---------------------------------------------------------------------------
__global__ __launch_bounds__(256) void xproj_kernel(
    const float* __restrict__ X, const float* __restrict__ W,
    const float* __restrict__ b, float* __restrict__ out)
{
    const int w = threadIdx.x >> 6;
    const int lane = threadIdx.x & 63;
    const int row0 = blockIdx.x * 16 + w * 4;

    float xr[4][24];
#pragma unroll
    for (int r = 0; r < 4; ++r)
#pragma unroll
        for (int i = 0; i < 24; ++i)
            xr[r][i] = X[(size_t)(row0 + r) * D_INNER + lane + i * 64];

    for (int n = 0; n < NSSM; ++n) {
        const float* wrow = W + (size_t)n * D_INNER;
        float a0 = 0.f, a1 = 0.f, a2 = 0.f, a3 = 0.f;
#pragma unroll
        for (int i = 0; i < 24; ++i) {
            const float wv = wrow[lane + i * 64];
            a0 = fmaf(xr[0][i], wv, a0);
            a1 = fmaf(xr[1][i], wv, a1);
            a2 = fmaf(xr[2][i], wv, a2);
            a3 = fmaf(xr[3][i], wv, a3);
        }
        const float bn_ = b[n];
        float accv[4] = {a0, a1, a2, a3};
#pragma unroll
        for (int r = 0; r < 4; ++r) {
            float a = accv[r];
            a += __shfl_xor(a, 32);
            a += __shfl_xor(a, 16);
            a += __shfl_xor(a, 8);
            a += __shfl_xor(a, 4);
            a += __shfl_xor(a, 2);
            a += __shfl_xor(a, 1);
            if (lane == 0) out[(size_t)(row0 + r) * NSSM + n] = a + bn_;
        }
    }
}

// ---------------------------------------------------------------------------
// Chunked selective scan, thread-per-channel (16 states in registers),
// 8-step register tiles with double-buffered prefetch (8 loads in flight;
// one memory latency per 8 steps instead of per step).
// addr(c,n,b,d) = c*NS + n*BD + b*D_INNER + d
// ---------------------------------------------------------------------------
__global__ __launch_bounds__(256) void scan_phase1(
    const float* __restrict__ xssm, const float* __restrict__ xconv,
    const float* __restrict__ dpW, const float* __restrict__ dpb,
    const float* __restrict__ A_log,
    float* __restrict__ Ap, float* __restrict__ Hp)
{
    const int d = blockIdx.x * 256 + threadIdx.x;
    const int c = blockIdx.y;
    const int b = blockIdx.z;

    const float w  = dpW[d];
    const float bb = dpb[d];
    float An[D_STATE];
#pragma unroll
    for (int n = 0; n < D_STATE; ++n)
        An[n] = -__expf(A_log[d * D_STATE + n]);

    const int bt0 = b * SEQ + c * LCH;

    float h[D_STATE], ap[D_STATE];
#pragma unroll
    for (int n = 0; n < D_STATE; ++n) { h[n] = 0.f; ap[n] = 1.f; }

    float cur[8];
#pragma unroll
    for (int j = 0; j < 8; ++j)
        cur[j] = xconv[(size_t)(bt0 + j) * D_INNER + d];

#pragma unroll
    for (int tb = 0; tb < LCH; tb += 8) {
        float nxt[8];
#pragma unroll
        for (int j = 0; j < 8; ++j) {
            int t = tb + 8 + j; t = (t < LCH) ? t : (LCH - 1);
            nxt[j] = xconv[(size_t)(bt0 + t) * D_INNER + d];
        }
#pragma unroll
        for (int j = 0; j < 8; ++j) {
            const float* row = xssm + (size_t)(bt0 + tb + j) * NSSM;
            const float dr = row[32];
            const float u = fmaf(dr, w, bb);
            const float delta = __logf(1.f + __expf(u));
            const float dx = delta * cur[j];
#pragma unroll
            for (int n = 0; n < D_STATE; ++n) {
                const float dA = __expf(delta * An[n]);
                h[n] = fmaf(dA, h[n], dx * row[n]);
                ap[n] *= dA;
            }
        }
#pragma unroll
        for (int j = 0; j < 8; ++j) cur[j] = nxt[j];
    }

    const size_t bd = (size_t)b * D_INNER + d;
#pragma unroll
    for (int n = 0; n < D_STATE; ++n) {
        Ap[(size_t)c * NS + (size_t)n * BD + bd] = ap[n];
        Hp[(size_t)c * NS + (size_t)n * BD + bd] = h[n];
    }
}

// Phase 2: serial prefix over chunk summaries, 8-batched loads; writes
// h-at-chunk-start IN PLACE into Ap.
__global__ __launch_bounds__(256) void scan_phase2(
    float* __restrict__ Ap, const float* __restrict__ Hp)
{
    const size_t s = (size_t)blockIdx.x * 256 + threadIdx.x;
    float carry = 0.f;
    for (int cb = 0; cb < NCH; cb += 8) {
        float av[8], hv[8];
#pragma unroll
        for (int j = 0; j < 8; ++j) av[j] = Ap[(size_t)(cb + j) * NS + s];
#pragma unroll
        for (int j = 0; j < 8; ++j) hv[j] = Hp[(size_t)(cb + j) * NS + s];
#pragma unroll
        for (int j = 0; j < 8; ++j) {
            Ap[(size_t)(cb + j) * NS + s] = carry;
            carry = fmaf(av[j], carry, hv[j]);
        }
    }
}

// Phase 3: replay with correct h_start; emit (y + x*D)*silu(z) into xconv.
__global__ __launch_bounds__(256) void scan_phase3(
    const float* __restrict__ xssm, float* __restrict__ xconv,
    const float* __restrict__ xz,
    const float* __restrict__ dpW, const float* __restrict__ dpb,
    const float* __restrict__ A_log, const float* __restrict__ Dvec,
    const float* __restrict__ Hs)
{
    const int d = blockIdx.x * 256 + threadIdx.x;
    const int c = blockIdx.y;
    const int b = blockIdx.z;

    const float w  = dpW[d];
    const float bb = dpb[d];
    const float Dd = Dvec[d];
    float An[D_STATE];
#pragma unroll
    for (int n = 0; n < D_STATE; ++n)
        An[n] = -__expf(A_log[d * D_STATE + n]);

    const int bt0 = b * SEQ + c * LCH;
    const size_t bd = (size_t)b * D_INNER + d;

    float h[D_STATE];
#pragma unroll
    for (int n = 0; n < D_STATE; ++n)
        h[n] = Hs[(size_t)c * NS + (size_t)n * BD + bd];

    float xc[8], zc[8];
#pragma unroll
    for (int j = 0; j < 8; ++j) {
        xc[j] = xconv[(size_t)(bt0 + j) * D_INNER + d];
        zc[j] = xz[(size_t)(bt0 + j) * NXZ + D_INNER + d];
    }

#pragma unroll
    for (int tb = 0; tb < LCH; tb += 8) {
        float xn[8], zn[8];
#pragma unroll
        for (int j = 0; j < 8; ++j) {
            int t = tb + 8 + j; t = (t < LCH) ? t : (LCH - 1);
            xn[j] = xconv[(size_t)(bt0 + t) * D_INNER + d];
            zn[j] = xz[(size_t)(bt0 + t) * NXZ + D_INNER + d];
        }
#pragma unroll
        for (int j = 0; j < 8; ++j) {
            const float* row = xssm + (size_t)(bt0 + tb + j) * NSSM;
            const float dr = row[32];
            const float u = fmaf(dr, w, bb);
            const float delta = __logf(1.f + __expf(u));
            const float dx = delta * xc[j];

            float y = 0.f;
#pragma unroll
            for (int n = 0; n < D_STATE; ++n) {
                const float dA = __expf(delta * An[n]);
                h[n] = fmaf(dA, h[n], dx * row[n]);
                y = fmaf(row[16 + n], h[n], y);
            }
            y = fmaf(xc[j], Dd, y);
            const float zv = zc[j];
            const float sg = zv / (1.f + __expf(-zv));
            xconv[(size_t)(bt0 + tb + j) * D_INNER + d] = y * sg;
        }
#pragma unroll
        for (int j = 0; j < 8; ++j) { xc[j] = xn[j]; zc[j] = zn[j]; }
    }
}

// ---------------------------------------------------------------------------
extern "C" void kernel_launch(void* const* d_in, const int* in_sizes, int n_in,
                              void* d_out, int out_size, void* d_ws, size_t ws_size,
                              hipStream_t stream)
{
    const float* x      = (const float*)d_in[0];
    const float* in_W   = (const float*)d_in[1];
    const float* in_b   = (const float*)d_in[2];
    const float* conv_W = (const float*)d_in[3];
    const float* conv_b = (const float*)d_in[4];
    const float* xp_W   = (const float*)d_in[5];
    const float* xp_b   = (const float*)d_in[6];
    const float* dp_W   = (const float*)d_in[7];
    const float* dp_b   = (const float*)d_in[8];
    const float* A_log  = (const float*)d_in[9];
    const float* Dvec   = (const float*)d_in[10];
    const float* out_W  = (const float*)d_in[11];
    const float* out_b  = (const float*)d_in[12];
    float* out = (float*)d_out;

    // workspace layout (float units)
    float* ws    = (float*)d_ws;
    float* xz    = ws;                                       // 12,582,912
    float* xconv = xz + (size_t)MROWS * NXZ;                 //  6,291,456
    float* xssm  = xconv + (size_t)MROWS * D_INNER;          //    135,168
    float* Hp    = xssm + (size_t)MROWS * NSSM;              //  3,145,728
    unsigned short* inWh  = (unsigned short*)(Hp + (size_t)NCH * NS);
    unsigned short* inWl  = inWh + (size_t)NXZ * D_MODEL;
    unsigned short* outWh = inWl + (size_t)NXZ * D_MODEL;
    unsigned short* outWl = outWh + (size_t)D_MODEL * D_INNER;
    float* ws_end = (float*)(outWl + (size_t)D_MODEL * D_INNER);

    // Ap (NCH*NS floats = 12.58 MB): prefer workspace if it fits, else d_out
    // (dead scratch between gemm1 consuming xh/xl and the final GEMM write).
    const size_t used_floats = (size_t)(ws_end - ws);
    const bool ap_in_ws = ws_size >= (used_floats + (size_t)NCH * NS) * sizeof(float);
    float* Ap = ap_in_ws ? ws_end : (float*)d_out;

    // x-split lives in d_out (consumed by gemm1 before Ap could be written)
    unsigned short* xh = (unsigned short*)d_out;
    unsigned short* xl = xh + (size_t)MROWS * D_MODEL;
    // xcg-split aliases the (dead-after-phase3) xz region
    unsigned short* xcgh = (unsigned short*)xz;
    unsigned short* xcgl = xcgh + (size_t)MROWS * D_INNER;

    // 0) split+retile x, in_W, out_W
    split_retile<<<(MROWS * D_MODEL) / 256, 256, 0, stream>>>(x, xh, xl, MROWS, D_MODEL);
    split_retile<<<(NXZ * D_MODEL) / 256, 256, 0, stream>>>(in_W, inWh, inWl, NXZ, D_MODEL);
    split_retile<<<(D_MODEL * D_INNER) / 256, 256, 0, stream>>>(out_W, outWh, outWl, D_MODEL, D_INNER);

    // 1) in-proj: xz = x @ in_W^T + in_b   (M=4096, N=3072, K=768)
    {
        dim3 grid(NXZ / 128, MROWS / 128);
        gemm_split<128, 128><<<grid, 256, 0, stream>>>(
            xh, xl, inWh, inWl, in_b, xz, MROWS, NXZ, D_MODEL);
    }
    // 2) depthwise conv + SiLU (float4 over d)
    conv_silu_kernel<<<(MROWS * D_INNER / 4) / 256, 256, 0, stream>>>(
        xz, conv_W, conv_b, xconv);
    // 3) x-proj
    xproj_kernel<<<MROWS / 16, 256, 0, stream>>>(xconv, xp_W, xp_b, xssm);
    // 4) chunked selective scan (thread-per-channel, 8-step prefetch tiles)
    {
        dim3 grid13(D_INNER / 256, NCH, BATCH);
        scan_phase1<<<grid13, 256, 0, stream>>>(xssm, xconv, dp_W, dp_b, A_log, Ap, Hp);
        scan_phase2<<<NS / 256, 256, 0, stream>>>(Ap, Hp);
        scan_phase3<<<grid13, 256, 0, stream>>>(xssm, xconv, xz, dp_W, dp_b, A_log,
                                                Dvec, Ap);
    }
    // 5) split+retile gated output (xz region is dead now)
    split_retile<<<(MROWS * D_INNER) / 256, 256, 0, stream>>>(xconv, xcgh, xcgl, MROWS, D_INNER);
    // 6) out-proj: out = y @ out_W^T + out_b  (M=4096, N=768, K=1536)
    {
        dim3 grid(D_MODEL / 64, MROWS / 64);
        gemm_split<64, 64><<<grid, 256, 0, stream>>>(
            xcgh, xcgl, outWh, outWl, out_b, out, MROWS, D_MODEL, D_INNER);
    }
}